// Round 2
// baseline (25.181 us; speedup 1.0000x reference)
//
#include <hip/hip_runtime.h>

// y[i,o,n] = sum_{j,k} x[j,(o-1)%56, n+k-1]*W[i,j,0,k]
//          + sum_{j,k} x[j,(o-2)%56, n+k-1]*W[i,j,1,k]
// x: (1,64,56,56) f32, W: (64,64,2,3) f32 [i,j,l,k], y: (1,64,56,56) f32

#define O_DIM 56
#define N_DIM 56
#define J_DIM 64
#define I_DIM 64

__global__ __launch_bounds__(256) void conv_shift_kernel(
    const float* __restrict__ x, const float* __restrict__ w, float* __restrict__ y)
{
    const int o    = blockIdx.x;        // 0..55
    const int ig   = blockIdx.y;        // 0..15 -> i in [ig*4, ig*4+4)
    const int tid  = threadIdx.x;       // 0..255
    const int wave = tid >> 6;          // 0..3  -> j in [wave*16, wave*16+16)
    const int n    = tid & 63;          // lane; active n < 56
    const int nc   = (n < N_DIM) ? n : (N_DIM - 1);

    const int rowA = (o + O_DIM - 1) % O_DIM;  // l=0 source row
    const int rowB = (o + O_DIM - 2) % O_DIM;  // l=1 source row

    const int i0 = ig * 4;
    const int j0 = wave * 16;

    float acc0 = 0.f, acc1 = 0.f, acc2 = 0.f, acc3 = 0.f;

    #pragma unroll 4
    for (int jj = 0; jj < 16; ++jj) {
        const int j = j0 + jj;
        const float* xa = x + (j * O_DIM + rowA) * N_DIM;
        const float* xb = x + (j * O_DIM + rowB) * N_DIM;

        const float aC = xa[nc];
        const float bC = xb[nc];
        const float aL = (nc > 0)         ? xa[nc - 1] : 0.f;
        const float aR = (nc < N_DIM - 1) ? xa[nc + 1] : 0.f;
        const float bL = (nc > 0)         ? xb[nc - 1] : 0.f;
        const float bR = (nc < N_DIM - 1) ? xb[nc + 1] : 0.f;

        // W[i,j,l,k] flat: (i*64 + j)*6 + l*3 + k ; block/wave-uniform -> s_load
        const float* w0 = w + ((i0 + 0) * J_DIM + j) * 6;
        const float* w1 = w + ((i0 + 1) * J_DIM + j) * 6;
        const float* w2 = w + ((i0 + 2) * J_DIM + j) * 6;
        const float* w3 = w + ((i0 + 3) * J_DIM + j) * 6;

        acc0 += aL * w0[0] + aC * w0[1] + aR * w0[2]
              + bL * w0[3] + bC * w0[4] + bR * w0[5];
        acc1 += aL * w1[0] + aC * w1[1] + aR * w1[2]
              + bL * w1[3] + bC * w1[4] + bR * w1[5];
        acc2 += aL * w2[0] + aC * w2[1] + aR * w2[2]
              + bL * w2[3] + bC * w2[4] + bR * w2[5];
        acc3 += aL * w3[0] + aC * w3[1] + aR * w3[2]
              + bL * w3[3] + bC * w3[4] + bR * w3[5];
    }

    // Cross-wave reduction over the j-split: red[wave][i_local][n]
    __shared__ float red[4][4][64];
    red[wave][0][n] = acc0;
    red[wave][1][n] = acc1;
    red[wave][2][n] = acc2;
    red[wave][3][n] = acc3;
    __syncthreads();

    // 224 outputs (4 i x 56 n); threads 0..223 each sum 4 partials
    if (tid < 4 * N_DIM) {
        const int il = tid / N_DIM;
        const int nn = tid % N_DIM;
        const float v = red[0][il][nn] + red[1][il][nn]
                      + red[2][il][nn] + red[3][il][nn];
        y[((i0 + il) * O_DIM + o) * N_DIM + nn] = v;
    }
}

extern "C" void kernel_launch(void* const* d_in, const int* in_sizes, int n_in,
                              void* d_out, int out_size, void* d_ws, size_t ws_size,
                              hipStream_t stream) {
    const float* x = (const float*)d_in[0];
    const float* w = (const float*)d_in[1];
    float* y = (float*)d_out;

    dim3 grid(O_DIM, I_DIM / 4);  // 56 x 16 = 896 blocks, 4 waves each
    conv_shift_kernel<<<grid, 256, 0, stream>>>(x, w, y);
}

// Round 3
// 16.953 us; speedup vs baseline: 1.4853x; 1.4853x over previous
//
#include <hip/hip_runtime.h>

// y[i,o,n] = sum_{j,k} x[j,(o-1)%56, n+k-1]*W[i,j,0,k]
//          + sum_{j,k} x[j,(o-2)%56, n+k-1]*W[i,j,1,k]
// x: (1,64,56,56) f32, W: (64,64,2,3) f32 [i,j,l,k], y: (1,64,56,56) f32
//
// Block = (o-pair, 4-i group), 256 threads (4 waves), j split across waves.
// o and o+1 share row (o-1): 3 x-rows feed 2*4*6 = 48 FMAs per j-iter.

#define O_DIM 56
#define N_DIM 56
#define J_DIM 64
#define I_DIM 64

__global__ __launch_bounds__(256) void conv_shift_kernel(
    const float* __restrict__ x, const float* __restrict__ w, float* __restrict__ y)
{
    const int op   = blockIdx.x;        // 0..27 -> o0 = 2*op, o1 = o0+1
    const int ig   = blockIdx.y;        // 0..15 -> i in [ig*4, ig*4+4)
    const int tid  = threadIdx.x;       // 0..255
    const int wave = tid >> 6;          // 0..3  -> j in [wave*16, wave*16+16)
    const int n    = tid & 63;          // lane; active n < 56
    const int nc   = (n < N_DIM) ? n : (N_DIM - 1);

    const int o0 = op * 2;
    // rows: o0 needs (o0-1, o0-2); o1 needs (o0, o0-1)  -> 3 distinct rows
    const int rowP = (o0 + O_DIM - 1) % O_DIM;   // o0-1
    const int rowQ = (o0 + O_DIM - 2) % O_DIM;   // o0-2
    const int rowR = o0;                          // o0

    const int i0 = ig * 4;
    const int j0 = wave * 16;

    float acc[2][4] = {{0.f,0.f,0.f,0.f},{0.f,0.f,0.f,0.f}};

    #pragma unroll 4
    for (int jj = 0; jj < 16; ++jj) {
        const int j = j0 + jj;
        const float* base = x + j * (O_DIM * N_DIM);
        const float* pP = base + rowP * N_DIM;
        const float* pQ = base + rowQ * N_DIM;
        const float* pR = base + rowR * N_DIM;

        const float cP = pP[nc], cQ = pQ[nc], cR = pR[nc];
        const float lP = (nc > 0) ? pP[nc - 1] : 0.f;
        const float lQ = (nc > 0) ? pQ[nc - 1] : 0.f;
        const float lR = (nc > 0) ? pR[nc - 1] : 0.f;
        const float rP = (nc < N_DIM - 1) ? pP[nc + 1] : 0.f;
        const float rQ = (nc < N_DIM - 1) ? pQ[nc + 1] : 0.f;
        const float rR = (nc < N_DIM - 1) ? pR[nc + 1] : 0.f;

        #pragma unroll
        for (int q = 0; q < 4; ++q) {
            const float* wq = w + ((i0 + q) * J_DIM + j) * 6;  // wave-uniform -> s_load
            const float w00 = wq[0], w01 = wq[1], w02 = wq[2];
            const float w10 = wq[3], w11 = wq[4], w12 = wq[5];
            // o0: A-row = rowP (l=0), B-row = rowQ (l=1)
            acc[0][q] += lP * w00 + cP * w01 + rP * w02
                       + lQ * w10 + cQ * w11 + rQ * w12;
            // o1: A-row = rowR (l=0), B-row = rowP (l=1)
            acc[1][q] += lR * w00 + cR * w01 + rR * w02
                       + lP * w10 + cP * w11 + rP * w12;
        }
    }

    // Cross-wave reduction over the j-split: red[wave][(o,i) slot][n]
    __shared__ float red[4][8][64];
    #pragma unroll
    for (int q = 0; q < 4; ++q) {
        red[wave][q][n]     = acc[0][q];
        red[wave][4 + q][n] = acc[1][q];
    }
    __syncthreads();

    // 448 outputs (2 o x 4 i x 56 n); 256 threads -> up to 2 each
    for (int t = tid; t < 8 * N_DIM; t += 256) {
        const int il = t / N_DIM;           // 0..7
        const int nn = t % N_DIM;
        const int oo = (il < 4) ? o0 : (o0 + 1);
        const int ii = i0 + (il & 3);
        const float v = red[0][il][nn] + red[1][il][nn]
                      + red[2][il][nn] + red[3][il][nn];
        y[(ii * O_DIM + oo) * N_DIM + nn] = v;
    }
}

extern "C" void kernel_launch(void* const* d_in, const int* in_sizes, int n_in,
                              void* d_out, int out_size, void* d_ws, size_t ws_size,
                              hipStream_t stream) {
    const float* x = (const float*)d_in[0];
    const float* w = (const float*)d_in[1];
    float* y = (float*)d_out;

    dim3 grid(O_DIM / 2, I_DIM / 4);  // 28 x 16 = 448 blocks, 4 waves each
    conv_shift_kernel<<<grid, 256, 0, stream>>>(x, w, y);
}